// Round 1
// baseline (2413.562 us; speedup 1.0000x reference)
//
#include <hip/hip_runtime.h>
#include <math.h>

#define NBATCH 4
#define TSEQ   2048
#define CDIM   1024
#define NHEAD  16
#define HDIM   64
#define MROWS  (NBATCH*TSEQ)   // 8192

// ======================= fp32 GEMM: C[M,N] = A[M,K]@B[K,N] (+bias) =======================
// 128x128 tile, BK=16, 256 threads, each thread 8x8 as 2x2 quads of 4x4.
#define BM 128
#define BN 128
#define BK 16
#define ASTR 132   // padded k-major A-tile stride (kills transpose-store conflicts)

__global__ __launch_bounds__(256) void gemm_f32(
    const float* __restrict__ A, const float* __restrict__ B,
    float* __restrict__ C, const float* __restrict__ bias,
    int M, int N, int K)
{
    __shared__ float As[2][BK][ASTR];   // [k][m]
    __shared__ float Bs[2][BK][BN];     // [k][n]

    const int tid = threadIdx.x;
    const int bm = blockIdx.x, bn = blockIdx.y;
    const int ty = tid >> 4, tx = tid & 15;

    float acc[2][2][4][4];
    #pragma unroll
    for (int a = 0; a < 2; ++a)
      #pragma unroll
      for (int b = 0; b < 2; ++b)
        #pragma unroll
        for (int i = 0; i < 4; ++i)
          #pragma unroll
          for (int j = 0; j < 4; ++j) acc[a][b][i][j] = 0.f;

    const int NT = K / BK;

    auto loadTile = [&](int kt, float4* ar, float4* br) {
      #pragma unroll
      for (int it = 0; it < 2; ++it) {
        int f = it * 256 + tid;
        int m = f >> 2, kg = f & 3;
        ar[it] = *reinterpret_cast<const float4*>(
            &A[(size_t)(bm * BM + m) * K + kt * BK + kg * 4]);
        int kr = f >> 5, ng = f & 31;
        br[it] = *reinterpret_cast<const float4*>(
            &B[(size_t)(kt * BK + kr) * N + bn * BN + ng * 4]);
      }
    };
    auto storeTile = [&](int buf, float4* ar, float4* br) {
      #pragma unroll
      for (int it = 0; it < 2; ++it) {
        int f = it * 256 + tid;
        int m = f >> 2, kg = f & 3;
        As[buf][kg * 4 + 0][m] = ar[it].x;
        As[buf][kg * 4 + 1][m] = ar[it].y;
        As[buf][kg * 4 + 2][m] = ar[it].z;
        As[buf][kg * 4 + 3][m] = ar[it].w;
        int kr = f >> 5, ng = f & 31;
        *reinterpret_cast<float4*>(&Bs[buf][kr][ng * 4]) = br[it];
      }
    };

    float4 a0[2], b0[2];
    loadTile(0, a0, b0);
    storeTile(0, a0, b0);

    for (int kt = 0; kt < NT; ++kt) {
      __syncthreads();
      float4 aN[2], bN[2];
      if (kt + 1 < NT) loadTile(kt + 1, aN, bN);
      const int buf = kt & 1;
      #pragma unroll
      for (int k = 0; k < BK; ++k) {
        float4 av0 = *reinterpret_cast<const float4*>(&As[buf][k][ty * 4]);
        float4 av1 = *reinterpret_cast<const float4*>(&As[buf][k][64 + ty * 4]);
        float4 bv0 = *reinterpret_cast<const float4*>(&Bs[buf][k][tx * 4]);
        float4 bv1 = *reinterpret_cast<const float4*>(&Bs[buf][k][64 + tx * 4]);
        float ar2[2][4] = {{av0.x, av0.y, av0.z, av0.w}, {av1.x, av1.y, av1.z, av1.w}};
        float br2[2][4] = {{bv0.x, bv0.y, bv0.z, bv0.w}, {bv1.x, bv1.y, bv1.z, bv1.w}};
        #pragma unroll
        for (int hi = 0; hi < 2; ++hi)
          #pragma unroll
          for (int i = 0; i < 4; ++i)
            #pragma unroll
            for (int hj = 0; hj < 2; ++hj)
              #pragma unroll
              for (int j = 0; j < 4; ++j)
                acc[hi][hj][i][j] += ar2[hi][i] * br2[hj][j];
      }
      if (kt + 1 < NT) storeTile((kt + 1) & 1, aN, bN);
    }

    #pragma unroll
    for (int hi = 0; hi < 2; ++hi) {
      #pragma unroll
      for (int i = 0; i < 4; ++i) {
        int row = bm * BM + hi * 64 + ty * 4 + i;
        #pragma unroll
        for (int hj = 0; hj < 2; ++hj) {
          int col = bn * BN + hj * 64 + tx * 4;
          float4 v = make_float4(acc[hi][hj][i][0], acc[hi][hj][i][1],
                                 acc[hi][hj][i][2], acc[hi][hj][i][3]);
          if (bias) {
            float4 bv = *reinterpret_cast<const float4*>(&bias[col]);
            v.x += bv.x; v.y += bv.y; v.z += bv.z; v.w += bv.w;
          }
          *reinterpret_cast<float4*>(&C[(size_t)row * N + col]) = v;
        }
      }
    }
}

// ======================= fp32 flash attention (causal) =======================
// One block = 64 Q rows of one (b,h). 256 threads as 16x16, 4x4 S-elements each.
// Q/K/V/ctx all in (B,T,C) layout; head slice is columns [h*64, h*64+64).
#define SP 68   // padded LDS stride (16B aligned, conflict-reducing)

__global__ __launch_bounds__(256) void attn_f32(
    const float* __restrict__ Q, const float* __restrict__ K,
    const float* __restrict__ V, float* __restrict__ ctx)
{
    __shared__ float Qs[HDIM][SP];  // [d][r], pre-scaled by 1/sqrt(D)
    __shared__ float Ks[HDIM][SP];  // [d][c]
    __shared__ float Vs[64][SP];    // [c][d]
    __shared__ float Ps[64][SP];    // [r][c]

    const int tid = threadIdx.x;
    const int qb = blockIdx.x;          // 0..31  (Q tile)
    const int bh = blockIdx.y;          // 0..63  (b*H + h)
    const int b  = bh >> 4, h = bh & 15;
    const int ti = tid >> 4, tj = tid & 15;

    const size_t rowbase = (size_t)(b * TSEQ) * CDIM + (size_t)h * HDIM;

    // load + scale + transpose Q tile (once)
    #pragma unroll
    for (int it = 0; it < 4; ++it) {
      int f = it * 256 + tid;
      int r = f >> 4, dg = f & 15;
      float4 qv = *reinterpret_cast<const float4*>(
          &Q[rowbase + (size_t)(qb * 64 + r) * CDIM + dg * 4]);
      const float sc = 0.125f;  // 1/sqrt(64)
      Qs[dg * 4 + 0][r] = qv.x * sc;
      Qs[dg * 4 + 1][r] = qv.y * sc;
      Qs[dg * 4 + 2][r] = qv.z * sc;
      Qs[dg * 4 + 3][r] = qv.w * sc;
    }

    float o[4][4];
    float mrow[4], lrow[4];
    #pragma unroll
    for (int i = 0; i < 4; ++i) {
      mrow[i] = -INFINITY; lrow[i] = 0.f;
      #pragma unroll
      for (int j = 0; j < 4; ++j) o[i][j] = 0.f;
    }

    for (int kb = 0; kb <= qb; ++kb) {
      // stage K (transposed) and V tiles
      #pragma unroll
      for (int it = 0; it < 4; ++it) {
        int f = it * 256 + tid;
        int c = f >> 4, dg = f & 15;
        size_t gaddr = rowbase + (size_t)(kb * 64 + c) * CDIM + dg * 4;
        float4 kv = *reinterpret_cast<const float4*>(&K[gaddr]);
        Ks[dg * 4 + 0][c] = kv.x;
        Ks[dg * 4 + 1][c] = kv.y;
        Ks[dg * 4 + 2][c] = kv.z;
        Ks[dg * 4 + 3][c] = kv.w;
        float4 vv = *reinterpret_cast<const float4*>(&V[gaddr]);
        *reinterpret_cast<float4*>(&Vs[c][dg * 4]) = vv;
      }
      __syncthreads();

      // S = (Q*scale) K^T
      float s[4][4];
      #pragma unroll
      for (int i = 0; i < 4; ++i)
        #pragma unroll
        for (int j = 0; j < 4; ++j) s[i][j] = 0.f;
      #pragma unroll 4
      for (int d = 0; d < HDIM; ++d) {
        float4 qv = *reinterpret_cast<const float4*>(&Qs[d][ti * 4]);
        float4 kv = *reinterpret_cast<const float4*>(&Ks[d][tj * 4]);
        float qa[4] = {qv.x, qv.y, qv.z, qv.w};
        float ka[4] = {kv.x, kv.y, kv.z, kv.w};
        #pragma unroll
        for (int i = 0; i < 4; ++i)
          #pragma unroll
          for (int j = 0; j < 4; ++j) s[i][j] += qa[i] * ka[j];
      }

      if (kb == qb) {  // causal mask on diagonal tile
        #pragma unroll
        for (int i = 0; i < 4; ++i)
          #pragma unroll
          for (int j = 0; j < 4; ++j)
            if (tj * 4 + j > ti * 4 + i) s[i][j] = -INFINITY;
      }

      // online softmax update (per-row stats across 16-lane column group)
      #pragma unroll
      for (int i = 0; i < 4; ++i) {
        float mt = fmaxf(fmaxf(s[i][0], s[i][1]), fmaxf(s[i][2], s[i][3]));
        mt = fmaxf(mt, __shfl_xor(mt, 1));
        mt = fmaxf(mt, __shfl_xor(mt, 2));
        mt = fmaxf(mt, __shfl_xor(mt, 4));
        mt = fmaxf(mt, __shfl_xor(mt, 8));
        float mnew  = fmaxf(mrow[i], mt);
        float alpha = __expf(mrow[i] - mnew);
        float p0 = __expf(s[i][0] - mnew);
        float p1 = __expf(s[i][1] - mnew);
        float p2 = __expf(s[i][2] - mnew);
        float p3 = __expf(s[i][3] - mnew);
        float lt = p0 + p1 + p2 + p3;
        lt += __shfl_xor(lt, 1);
        lt += __shfl_xor(lt, 2);
        lt += __shfl_xor(lt, 4);
        lt += __shfl_xor(lt, 8);
        lrow[i] = lrow[i] * alpha + lt;
        mrow[i] = mnew;
        o[i][0] *= alpha; o[i][1] *= alpha; o[i][2] *= alpha; o[i][3] *= alpha;
        *reinterpret_cast<float4*>(&Ps[ti * 4 + i][tj * 4]) = make_float4(p0, p1, p2, p3);
      }
      __syncthreads();

      // O += P @ V
      #pragma unroll 4
      for (int c4 = 0; c4 < 16; ++c4) {
        float4 pv[4];
        #pragma unroll
        for (int i = 0; i < 4; ++i)
          pv[i] = *reinterpret_cast<const float4*>(&Ps[ti * 4 + i][c4 * 4]);
        #pragma unroll
        for (int jj = 0; jj < 4; ++jj) {
          float4 vv = *reinterpret_cast<const float4*>(&Vs[c4 * 4 + jj][tj * 4]);
          #pragma unroll
          for (int i = 0; i < 4; ++i) {
            float pc = (jj == 0) ? pv[i].x : (jj == 1) ? pv[i].y : (jj == 2) ? pv[i].z : pv[i].w;
            o[i][0] += pc * vv.x;
            o[i][1] += pc * vv.y;
            o[i][2] += pc * vv.z;
            o[i][3] += pc * vv.w;
          }
        }
      }
      __syncthreads();
    }

    // normalize + write ctx
    #pragma unroll
    for (int i = 0; i < 4; ++i) {
      float inv = 1.f / lrow[i];
      float4 v = make_float4(o[i][0] * inv, o[i][1] * inv, o[i][2] * inv, o[i][3] * inv);
      *reinterpret_cast<float4*>(
          &ctx[rowbase + (size_t)(qb * 64 + ti * 4 + i) * CDIM + tj * 4]) = v;
    }
}

// ======================= launch =======================
extern "C" void kernel_launch(void* const* d_in, const int* in_sizes, int n_in,
                              void* d_out, int out_size, void* d_ws, size_t ws_size,
                              hipStream_t stream)
{
    const float* x  = (const float*)d_in[0];
    const float* Wq = (const float*)d_in[1];
    const float* Wk = (const float*)d_in[2];
    const float* Wv = (const float*)d_in[3];
    const float* Wo = (const float*)d_in[4];
    const float* bo = (const float*)d_in[5];
    float* out = (float*)d_out;

    float* ws = (float*)d_ws;
    const size_t per = (size_t)MROWS * CDIM;   // 8M floats = 32 MB
    float* Qm = ws;
    float* Km = ws + per;
    float* Vm = ws + 2 * per;
    float* Cx = ws + 3 * per;

    dim3 gg(MROWS / BM, CDIM / BN), bb(256);
    hipLaunchKernelGGL(gemm_f32, gg, bb, 0, stream, x,  Wq, Qm, (const float*)nullptr, MROWS, CDIM, CDIM);
    hipLaunchKernelGGL(gemm_f32, gg, bb, 0, stream, x,  Wk, Km, (const float*)nullptr, MROWS, CDIM, CDIM);
    hipLaunchKernelGGL(gemm_f32, gg, bb, 0, stream, x,  Wv, Vm, (const float*)nullptr, MROWS, CDIM, CDIM);
    hipLaunchKernelGGL(attn_f32, dim3(TSEQ / 64, NBATCH * NHEAD), bb, 0, stream, Qm, Km, Vm, Cx);
    hipLaunchKernelGGL(gemm_f32, gg, bb, 0, stream, Cx, Wo, out, bo, MROWS, CDIM, CDIM);
}

// Round 2
// 649.119 us; speedup vs baseline: 3.7182x; 3.7182x over previous
//
#include <hip/hip_runtime.h>
#include <math.h>
#include <stdint.h>

#define TSEQ 2048
#define NB   4
#define CD   1024
#define NH   16
#define HD   64
#define MR   8192   // NB*TSEQ

typedef __bf16 bf16x8 __attribute__((ext_vector_type(8)));
typedef float  f32x4  __attribute__((ext_vector_type(4)));

// fp32 -> bf16 round-to-nearest-even
__device__ __forceinline__ unsigned short f2b(float f) {
  unsigned u = __float_as_uint(f);
  u += 0x7fffu + ((u >> 16) & 1u);
  return (unsigned short)(u >> 16);
}

// async global->LDS, 16B per lane. LDS dest = wave-uniform base + lane*16 (HW).
__device__ __forceinline__ void gll16(const void* g, const void* l) {
  __builtin_amdgcn_global_load_lds(
      (const __attribute__((address_space(1))) unsigned*)(uintptr_t)g,
      (__attribute__((address_space(3))) unsigned*)(uintptr_t)l, 16, 0, 0);
}

// ---------------- cast x (8192x1024 f32 -> bf16, same layout) ----------------
__global__ __launch_bounds__(256) void cast_x_k(const float* __restrict__ in,
                                                unsigned short* __restrict__ out) {
  int i = blockIdx.x * 256 + threadIdx.x;          // 1M threads, 8 elems each
  const float4* p = (const float4*)in;
  float4 a = p[2 * i], b = p[2 * i + 1];
  uint4 o;
  o.x = f2b(a.x) | ((unsigned)f2b(a.y) << 16);
  o.y = f2b(a.z) | ((unsigned)f2b(a.w) << 16);
  o.z = f2b(b.x) | ((unsigned)f2b(b.y) << 16);
  o.w = f2b(b.z) | ((unsigned)f2b(b.w) << 16);
  ((uint4*)out)[i] = o;
}

// ------------- cast + transpose weights: (K,N) f32 -> (N,K) bf16 -------------
__global__ __launch_bounds__(256) void castT_k(
    const float* __restrict__ w0, const float* __restrict__ w1,
    const float* __restrict__ w2, const float* __restrict__ w3,
    unsigned short* __restrict__ o0, unsigned short* __restrict__ o1,
    unsigned short* __restrict__ o2, unsigned short* __restrict__ o3) {
  const float* W = blockIdx.z == 0 ? w0 : blockIdx.z == 1 ? w1 : blockIdx.z == 2 ? w2 : w3;
  unsigned short* O = blockIdx.z == 0 ? o0 : blockIdx.z == 1 ? o1 : blockIdx.z == 2 ? o2 : o3;
  __shared__ float t[32][33];
  int tx = threadIdx.x & 31, ty = threadIdx.x >> 5;  // 32 x 8
  #pragma unroll
  for (int i = 0; i < 4; ++i)
    t[ty + i * 8][tx] = W[(size_t)(blockIdx.y * 32 + ty + i * 8) * CD + blockIdx.x * 32 + tx];
  __syncthreads();
  #pragma unroll
  for (int i = 0; i < 4; ++i)
    O[(size_t)(blockIdx.x * 32 + ty + i * 8) * CD + blockIdx.y * 32 + tx] = f2b(t[tx][ty + i * 8]);
}

// ---------------- bf16 GEMM: C = A(M,K) @ Bt(N,K)^T, M=8192,N=K=1024 ---------
// 128x128 tile, BK=32, 4 waves 2x2, each wave 64x64 = 4x4 mfma_16x16x32 frags.
// MODE 0: bf16 out, natural (M,N). MODE 1: bf16 out, V^T (B,H,D,T) layout.
// MODE 2: f32 out + bias.
template <int MODE>
__global__ __launch_bounds__(256) void gemm_k(const unsigned short* __restrict__ A,
                                              const unsigned short* __restrict__ Bt,
                                              void* __restrict__ out,
                                              const float* __restrict__ bias) {
  __shared__ __align__(16) unsigned short Asl[128 * 32];  // [m][k] linear
  __shared__ __align__(16) unsigned short Bsl[128 * 32];  // [n][k] linear
  const int tid = threadIdx.x, lane = tid & 63, w = tid >> 6;
  const int li = lane & 15, lg = lane >> 4;
  const int bm = blockIdx.x, bn = blockIdx.y;
  const int wr = w >> 1, wc = w & 1;

  f32x4 acc[4][4];
  #pragma unroll
  for (int mi = 0; mi < 4; ++mi)
    #pragma unroll
    for (int ni = 0; ni < 4; ++ni) acc[mi][ni] = (f32x4){0.f, 0.f, 0.f, 0.f};

  for (int kt = 0; kt < 32; ++kt) {
    #pragma unroll
    for (int it = 0; it < 2; ++it) {
      int c = (w * 2 + it) * 64 + lane;         // 16B-chunk index 0..511
      int r = c >> 2, ko = (c & 3) * 8;         // row, k-offset(elems)
      gll16(A  + (size_t)(bm * 128 + r) * CD + kt * 32 + ko, (const char*)Asl + (w * 2 + it) * 1024);
      gll16(Bt + (size_t)(bn * 128 + r) * CD + kt * 32 + ko, (const char*)Bsl + (w * 2 + it) * 1024);
    }
    __syncthreads();   // drains vmcnt (compiler) -> tiles resident
    bf16x8 af[4], bfr[4];
    #pragma unroll
    for (int mi = 0; mi < 4; ++mi)
      af[mi] = *(const bf16x8*)&Asl[(wr * 64 + mi * 16 + li) * 32 + lg * 8];
    #pragma unroll
    for (int ni = 0; ni < 4; ++ni)
      bfr[ni] = *(const bf16x8*)&Bsl[(wc * 64 + ni * 16 + li) * 32 + lg * 8];
    #pragma unroll
    for (int mi = 0; mi < 4; ++mi)
      #pragma unroll
      for (int ni = 0; ni < 4; ++ni)
        acc[mi][ni] = __builtin_amdgcn_mfma_f32_16x16x32_bf16(af[mi], bfr[ni], acc[mi][ni], 0, 0, 0);
    __syncthreads();   // all reads done before next-tile overwrite
  }

  // epilogue: C/D layout col=lane&15, row=(lane>>4)*4+reg  [verified m89/m91]
  #pragma unroll
  for (int mi = 0; mi < 4; ++mi)
    #pragma unroll
    for (int ni = 0; ni < 4; ++ni)
      #pragma unroll
      for (int r = 0; r < 4; ++r) {
        int row = bm * 128 + wr * 64 + mi * 16 + lg * 4 + r;
        int col = bn * 128 + wc * 64 + ni * 16 + li;
        float v = acc[mi][ni][r];
        if constexpr (MODE == 0) {
          ((unsigned short*)out)[(size_t)row * CD + col] = f2b(v);
        } else if constexpr (MODE == 1) {
          int b = row >> 11, t = row & 2047;   // row = b*TSEQ + t
          ((unsigned short*)out)[(size_t)(b * CD + col) * TSEQ + t] = f2b(v);
        } else {
          ((float*)out)[(size_t)row * CD + col] = v + bias[col];
        }
      }
}

// ---------------- bf16 MFMA flash attention (causal) -------------------------
// Block = 4 independent waves; wave w owns 16 q-rows of one (b,h). KVBLK=64.
// Swapped QK^T: mfma(A=K,B=Q) -> lane holds S[q=lane&15][k=16*mf+(lane>>4)*4+r].
// Softmax reduce = shfl_xor(16,32). P re-fragmented through per-wave LDS tile.
// PV: mfma(A=P,B=V^T-frag) -> lane holds ctx[q=(lane>>4)*4+r][d=nf*16+lane&15].
__global__ __launch_bounds__(256) void attn_k(const unsigned short* __restrict__ Q,
                                              const unsigned short* __restrict__ K,
                                              const unsigned short* __restrict__ Vt,
                                              unsigned short* __restrict__ Cx) {
  __shared__ __align__(16) unsigned short P[4][16][88];  // [wave][q][k], pad 88
  const int tid = threadIdx.x, w = tid >> 6, lane = tid & 63;
  const int li = lane & 15, lg = lane >> 4;
  const int qb = blockIdx.x, bh = blockIdx.y;
  const int b = bh >> 4, h = bh & 15;
  const int qoff = w * 16 + li;                      // q within 64-row block
  const int qrow = b * TSEQ + qb * 64 + qoff;        // global token row
  const float SC = 0.18033688011112042f;             // log2(e)/sqrt(64)

  bf16x8 qf[2];
  #pragma unroll
  for (int hf = 0; hf < 2; ++hf)
    qf[hf] = *(const bf16x8*)&Q[(size_t)qrow * CD + h * 64 + hf * 32 + lg * 8];

  f32x4 o[4];
  #pragma unroll
  for (int n = 0; n < 4; ++n) o[n] = (f32x4){0.f, 0.f, 0.f, 0.f};
  float m = -INFINITY, lsum = 0.f;

  for (int kb = 0; kb <= qb; ++kb) {
    // S^T = K @ Q^T  (contraction over d=64, two K=32 mfmas per 16-k frag)
    f32x4 st[4];
    #pragma unroll
    for (int mf = 0; mf < 4; ++mf) st[mf] = (f32x4){0.f, 0.f, 0.f, 0.f};
    #pragma unroll
    for (int mf = 0; mf < 4; ++mf)
      #pragma unroll
      for (int hf = 0; hf < 2; ++hf) {
        bf16x8 kf = *(const bf16x8*)&K[(size_t)(b * TSEQ + kb * 64 + mf * 16 + li) * CD +
                                       h * 64 + hf * 32 + lg * 8];
        st[mf] = __builtin_amdgcn_mfma_f32_16x16x32_bf16(kf, qf[hf], st[mf], 0, 0, 0);
      }

    if (kb == qb) {  // causal mask on the diagonal block
      #pragma unroll
      for (int mf = 0; mf < 4; ++mf)
        #pragma unroll
        for (int r = 0; r < 4; ++r)
          if (mf * 16 + lg * 4 + r > qoff) st[mf][r] = -INFINITY;
    }

    // online softmax (raw-S domain; scale folded into SC)
    float rmax = -INFINITY;
    #pragma unroll
    for (int mf = 0; mf < 4; ++mf)
      #pragma unroll
      for (int r = 0; r < 4; ++r) rmax = fmaxf(rmax, st[mf][r]);
    rmax = fmaxf(rmax, __shfl_xor(rmax, 16));
    rmax = fmaxf(rmax, __shfl_xor(rmax, 32));
    float mnew = fmaxf(m, rmax);
    float alpha = exp2f((m - mnew) * SC);
    float p[4][4], psum = 0.f;
    #pragma unroll
    for (int mf = 0; mf < 4; ++mf)
      #pragma unroll
      for (int r = 0; r < 4; ++r) {
        p[mf][r] = exp2f((st[mf][r] - mnew) * SC);
        psum += p[mf][r];
      }
    psum += __shfl_xor(psum, 16);
    psum += __shfl_xor(psum, 32);
    lsum = lsum * alpha + psum;
    m = mnew;

    // P -> per-wave LDS tile (bf16), then re-fragment for PV
    #pragma unroll
    for (int mf = 0; mf < 4; ++mf) {
      uint2 pk;
      pk.x = f2b(p[mf][0]) | ((unsigned)f2b(p[mf][1]) << 16);
      pk.y = f2b(p[mf][2]) | ((unsigned)f2b(p[mf][3]) << 16);
      *(uint2*)&P[w][li][mf * 16 + lg * 4] = pk;
    }
    asm volatile("s_waitcnt lgkmcnt(0)" ::: "memory");  // cross-lane LDS dep
    __builtin_amdgcn_sched_barrier(0);                  // rule #18

    float al[4];
    #pragma unroll
    for (int r = 0; r < 4; ++r) al[r] = __shfl(alpha, lg * 4 + r);
    #pragma unroll
    for (int n = 0; n < 4; ++n)
      #pragma unroll
      for (int r = 0; r < 4; ++r) o[n][r] *= al[r];

    bf16x8 pa[2];
    #pragma unroll
    for (int hf = 0; hf < 2; ++hf)
      pa[hf] = *(const bf16x8*)&P[w][li][hf * 32 + lg * 8];
    #pragma unroll
    for (int n = 0; n < 4; ++n)
      #pragma unroll
      for (int hf = 0; hf < 2; ++hf) {
        bf16x8 vf = *(const bf16x8*)&Vt[(size_t)(b * CD + h * 64 + n * 16 + li) * TSEQ +
                                        kb * 64 + hf * 32 + lg * 8];
        o[n] = __builtin_amdgcn_mfma_f32_16x16x32_bf16(pa[hf], vf, o[n], 0, 0, 0);
      }
  }

  float ls[4];
  #pragma unroll
  for (int r = 0; r < 4; ++r) ls[r] = __shfl(lsum, lg * 4 + r);
  #pragma unroll
  for (int n = 0; n < 4; ++n)
    #pragma unroll
    for (int r = 0; r < 4; ++r) {
      int row = b * TSEQ + qb * 64 + w * 16 + lg * 4 + r;
      Cx[(size_t)row * CD + h * 64 + n * 16 + li] = f2b(o[n][r] / ls[r]);
    }
}

// ---------------- launch ----------------
extern "C" void kernel_launch(void* const* d_in, const int* in_sizes, int n_in,
                              void* d_out, int out_size, void* d_ws, size_t ws_size,
                              hipStream_t stream) {
  const float* x  = (const float*)d_in[0];
  const float* Wq = (const float*)d_in[1];
  const float* Wk = (const float*)d_in[2];
  const float* Wv = (const float*)d_in[3];
  const float* Wo = (const float*)d_in[4];
  const float* bo = (const float*)d_in[5];
  float* out = (float*)d_out;

  char* W = (char*)d_ws;
  unsigned short* xb  = (unsigned short*)(W);                    // 16 MB
  unsigned short* WqT = (unsigned short*)(W + (16u << 20));      //  2 MB
  unsigned short* WkT = (unsigned short*)(W + (18u << 20));
  unsigned short* WvT = (unsigned short*)(W + (20u << 20));
  unsigned short* WoT = (unsigned short*)(W + (22u << 20));
  unsigned short* Qm  = (unsigned short*)(W + (24u << 20));      // 16 MB (B,T,C)
  unsigned short* Km  = (unsigned short*)(W + (40u << 20));      // 16 MB (B,T,C)
  unsigned short* Vt  = (unsigned short*)(W + (56u << 20));      // 16 MB (B,H,D,T)
  unsigned short* Cx  = (unsigned short*)(W + (72u << 20));      // 16 MB (B,T,C)

  hipLaunchKernelGGL(cast_x_k, dim3(4096), dim3(256), 0, stream, x, xb);
  hipLaunchKernelGGL(castT_k, dim3(32, 32, 4), dim3(256), 0, stream,
                     Wq, Wk, Wv, Wo, WqT, WkT, WvT, WoT);
  hipLaunchKernelGGL((gemm_k<0>), dim3(64, 8), dim3(256), 0, stream, xb, WqT, (void*)Qm, (const float*)nullptr);
  hipLaunchKernelGGL((gemm_k<0>), dim3(64, 8), dim3(256), 0, stream, xb, WkT, (void*)Km, (const float*)nullptr);
  hipLaunchKernelGGL((gemm_k<1>), dim3(64, 8), dim3(256), 0, stream, xb, WvT, (void*)Vt, (const float*)nullptr);
  hipLaunchKernelGGL(attn_k, dim3(32, 64), dim3(256), 0, stream, Qm, Km, Vt, Cx);
  hipLaunchKernelGGL((gemm_k<2>), dim3(64, 8), dim3(256), 0, stream, Cx, WoT, (void*)out, bo);
}

// Round 4
// 306.877 us; speedup vs baseline: 7.8649x; 2.1152x over previous
//
#include <hip/hip_runtime.h>
#include <math.h>
#include <stdint.h>

#define TSEQ 2048
#define NB   4
#define CD   1024
#define NH   16
#define HD   64
#define MR   8192   // NB*TSEQ

typedef __bf16 bf16x8 __attribute__((ext_vector_type(8)));
typedef float  f32x4  __attribute__((ext_vector_type(4)));
typedef float  f32x16 __attribute__((ext_vector_type(16)));

// fp32 -> bf16 round-to-nearest-even
__device__ __forceinline__ unsigned short f2b(float f) {
  unsigned u = __float_as_uint(f);
  u += 0x7fffu + ((u >> 16) & 1u);
  return (unsigned short)(u >> 16);
}
__device__ __forceinline__ unsigned cvtpk(float lo, float hi) {
  unsigned r;
  asm("v_cvt_pk_bf16_f32 %0, %1, %2" : "=v"(r) : "v"(lo), "v"(hi));
  return r;
}

// async global->LDS, 16B per lane: LDS dest = wave-uniform base + lane*16.
__device__ __forceinline__ void gll16(const void* g, const void* l) {
  __builtin_amdgcn_global_load_lds(
      (const __attribute__((address_space(1))) unsigned*)(uintptr_t)g,
      (__attribute__((address_space(3))) unsigned*)(uintptr_t)l, 16, 0, 0);
}

// ---------------- cast x (8192x1024 f32 -> bf16, same layout) ----------------
__global__ __launch_bounds__(256) void cast_x_k(const float* __restrict__ in,
                                                unsigned short* __restrict__ out) {
  int i = blockIdx.x * 256 + threadIdx.x;
  const float4* p = (const float4*)in;
  float4 a = p[2 * i], b = p[2 * i + 1];
  uint4 o;
  o.x = f2b(a.x) | ((unsigned)f2b(a.y) << 16);
  o.y = f2b(a.z) | ((unsigned)f2b(a.w) << 16);
  o.z = f2b(b.x) | ((unsigned)f2b(b.y) << 16);
  o.w = f2b(b.z) | ((unsigned)f2b(b.w) << 16);
  ((uint4*)out)[i] = o;
}

// ------------- cast + transpose weights: (K,N) f32 -> (N,K) bf16 -------------
__global__ __launch_bounds__(256) void castT_k(
    const float* __restrict__ w0, const float* __restrict__ w1,
    const float* __restrict__ w2, const float* __restrict__ w3,
    unsigned short* __restrict__ o0, unsigned short* __restrict__ o1,
    unsigned short* __restrict__ o2, unsigned short* __restrict__ o3) {
  const float* W = blockIdx.z == 0 ? w0 : blockIdx.z == 1 ? w1 : blockIdx.z == 2 ? w2 : w3;
  unsigned short* O = blockIdx.z == 0 ? o0 : blockIdx.z == 1 ? o1 : blockIdx.z == 2 ? o2 : o3;
  __shared__ float t[32][33];
  int tx = threadIdx.x & 31, ty = threadIdx.x >> 5;
  #pragma unroll
  for (int i = 0; i < 4; ++i)
    t[ty + i * 8][tx] = W[(size_t)(blockIdx.y * 32 + ty + i * 8) * CD + blockIdx.x * 32 + tx];
  __syncthreads();
  #pragma unroll
  for (int i = 0; i < 4; ++i)
    O[(size_t)(blockIdx.x * 32 + ty + i * 8) * CD + blockIdx.y * 32 + tx] = f2b(t[tx][ty + i * 8]);
}

// ---------------- bf16 GEMM: C = A(M,K) @ Bt(N,K)^T -------------------------
// 128x128 tile, BK=32, 4 waves 2x2. MODE 3: fused QKV (N=3072), routes output
// per bn-segment: Q natural, K natural, V -> (B,H,D,T). MODE 2: f32 out +bias.
template <int MODE>
__global__ __launch_bounds__(256) void gemm_k(const unsigned short* __restrict__ A,
                                              const unsigned short* __restrict__ Bt,
                                              void* __restrict__ o0, void* __restrict__ o1,
                                              void* __restrict__ o2,
                                              const float* __restrict__ bias) {
  __shared__ __align__(16) unsigned short Asl[128 * 32];
  __shared__ __align__(16) unsigned short Bsl[128 * 32];
  const int tid = threadIdx.x, lane = tid & 63, w = tid >> 6;
  const int li = lane & 15, lg = lane >> 4;
  const int bm = blockIdx.x, bn = blockIdx.y;
  const int wr = w >> 1, wc = w & 1;

  f32x4 acc[4][4];
  #pragma unroll
  for (int mi = 0; mi < 4; ++mi)
    #pragma unroll
    for (int ni = 0; ni < 4; ++ni) acc[mi][ni] = (f32x4){0.f, 0.f, 0.f, 0.f};

  for (int kt = 0; kt < 32; ++kt) {
    #pragma unroll
    for (int it = 0; it < 2; ++it) {
      int c = (w * 2 + it) * 64 + lane;
      int r = c >> 2, ko = (c & 3) * 8;
      gll16(A  + (size_t)(bm * 128 + r) * CD + kt * 32 + ko, (const char*)Asl + (w * 2 + it) * 1024);
      gll16(Bt + (size_t)(bn * 128 + r) * CD + kt * 32 + ko, (const char*)Bsl + (w * 2 + it) * 1024);
    }
    __syncthreads();
    bf16x8 af[4], bfr[4];
    #pragma unroll
    for (int mi = 0; mi < 4; ++mi)
      af[mi] = *(const bf16x8*)&Asl[(wr * 64 + mi * 16 + li) * 32 + lg * 8];
    #pragma unroll
    for (int ni = 0; ni < 4; ++ni)
      bfr[ni] = *(const bf16x8*)&Bsl[(wc * 64 + ni * 16 + li) * 32 + lg * 8];
    #pragma unroll
    for (int mi = 0; mi < 4; ++mi)
      #pragma unroll
      for (int ni = 0; ni < 4; ++ni)
        acc[mi][ni] = __builtin_amdgcn_mfma_f32_16x16x32_bf16(af[mi], bfr[ni], acc[mi][ni], 0, 0, 0);
    __syncthreads();
  }

  // C/D layout: col=lane&15, row=(lane>>4)*4+reg
  #pragma unroll
  for (int mi = 0; mi < 4; ++mi)
    #pragma unroll
    for (int ni = 0; ni < 4; ++ni)
      #pragma unroll
      for (int r = 0; r < 4; ++r) {
        int row = bm * 128 + wr * 64 + mi * 16 + lg * 4 + r;
        int col = bn * 128 + wc * 64 + ni * 16 + li;
        float v = acc[mi][ni][r];
        if constexpr (MODE == 3) {
          int seg = col >> 10, c2 = col & 1023;
          if (seg == 0) {
            ((unsigned short*)o0)[(size_t)row * CD + c2] = f2b(v);
          } else if (seg == 1) {
            ((unsigned short*)o1)[(size_t)row * CD + c2] = f2b(v);
          } else {
            int b = row >> 11, t = row & 2047;
            ((unsigned short*)o2)[(size_t)(b * CD + c2) * TSEQ + t] = f2b(v);
          }
        } else {
          ((float*)o0)[(size_t)row * CD + col] = v + bias[col];
        }
      }
}

// ---------------- bf16 MFMA flash attention (causal), 32x32x16 ---------------
// Block = 4 waves; wave w owns 32 q-rows; q-tile = 128 rows. Block processes
// tiles {pj, 15-pj} -> uniform 68 kb-units. KVBLK=32.
// QK^T swapped: mfma(A=K,B=Q) -> lane owns q=lane&31, 16 k-vals.
// PV as O^T = mfma(A=V^T, B=P^T): P^T frag = own p + shfl_xor(32) partner.
// K/V staged in LDS frag-major via global_load_lds, dbuf, counted vmcnt.
__global__ __launch_bounds__(256) void attn_k(const unsigned short* __restrict__ Qm,
                                              const unsigned short* __restrict__ Km,
                                              const unsigned short* __restrict__ Vt,
                                              unsigned short* __restrict__ Cx) {
  __shared__ __align__(16) unsigned short Kt[2][2048];  // 4 frags * 64 lanes * 16B
  __shared__ __align__(16) unsigned short Vs[2][2048];
  const int tid = threadIdx.x, w = tid >> 6, lane = tid & 63;
  const int q32 = lane & 31, hi = lane >> 5;
  const int pj = blockIdx.x, bh = blockIdx.y;
  const int b = bh >> 4, h = bh & 15;
  const float SC = 0.18033688011112042f;  // log2(e)/sqrt(64)

  #pragma unroll 1
  for (int pass = 0; pass < 2; ++pass) {
    const int qt = pass ? (15 - pj) : pj;
    const int qloc = qt * 128 + w * 32 + q32;           // q local to (b,h)
    const size_t qrow = (size_t)(b * TSEQ) + qloc;
    const int NKB = qt * 4 + 4;
    const int diag = qt * 4 + w;

    bf16x8 qf[4];
    #pragma unroll
    for (int dc = 0; dc < 4; ++dc)
      qf[dc] = *(const bf16x8*)&Qm[qrow * CD + h * 64 + dc * 16 + hi * 8];

    f32x16 oc0, oc1;
    #pragma unroll
    for (int r = 0; r < 16; ++r) { oc0[r] = 0.f; oc1[r] = 0.f; }
    float m = -INFINITY, lsum = 0.f;

    // stage helpers: wave w stages K-frag dc=w and V-frag f=w (kchunk=w>>1,dh=w&1)
    auto stage = [&](int kb, int buf) {
      gll16(Km + (size_t)(b * TSEQ + kb * 32 + q32) * CD + h * 64 + w * 16 + hi * 8,
            (const char*)&Kt[buf][w * 512]);
      gll16(Vt + ((size_t)b * CD + h * 64 + (w & 1) * 32 + q32) * TSEQ + kb * 32 + (w >> 1) * 16 + hi * 8,
            (const char*)&Vs[buf][w * 512]);
    };

    stage(0, 0);
    #pragma unroll 1
    for (int kb = 0; kb < NKB; ++kb) {
      const int buf = kb & 1;
      if (kb + 1 < NKB) {
        stage(kb + 1, buf ^ 1);
        asm volatile("s_waitcnt vmcnt(2)" ::: "memory");
      } else {
        asm volatile("s_waitcnt vmcnt(0)" ::: "memory");
      }
      __builtin_amdgcn_s_barrier();
      __builtin_amdgcn_sched_barrier(0);

      // S^T = K @ Q^T over d=64 (4 x K=16)
      f32x16 st;
      #pragma unroll
      for (int r = 0; r < 16; ++r) st[r] = 0.f;
      #pragma unroll
      for (int dc = 0; dc < 4; ++dc) {
        bf16x8 kf = *(const bf16x8*)&Kt[buf][dc * 512 + lane * 8];
        st = __builtin_amdgcn_mfma_f32_32x32x16_bf16(kf, qf[dc], st, 0, 0, 0);
      }

      if (kb >= diag) {  // causal mask (beyond-diagonal tiles fully masked)
        #pragma unroll
        for (int r = 0; r < 16; ++r) {
          int kloc = kb * 32 + (r & 3) + 8 * (r >> 2) + 4 * hi;
          if (kloc > qloc) st[r] = -INFINITY;
        }
      }

      // online softmax (lanes l, l+32 share q -> xor32 reduce)
      float rmax = st[0];
      #pragma unroll
      for (int r = 1; r < 16; ++r) rmax = fmaxf(rmax, st[r]);
      rmax = fmaxf(rmax, __shfl_xor(rmax, 32));
      float mnew = fmaxf(m, rmax);
      float alpha = exp2f((m - mnew) * SC);
      float p[16], psum = 0.f;
      #pragma unroll
      for (int r = 0; r < 16; ++r) {
        p[r] = exp2f((st[r] - mnew) * SC);
        psum += p[r];
      }
      psum += __shfl_xor(psum, 32);
      lsum = lsum * alpha + psum;
      m = mnew;
      #pragma unroll
      for (int r = 0; r < 16; ++r) { oc0[r] *= alpha; oc1[r] *= alpha; }

      // pack P -> bf16 pairs; W[s][t] covers k = 8s + 4hi + 2t + {0,1}
      unsigned W[4][2], X[4][2];
      #pragma unroll
      for (int s = 0; s < 4; ++s)
        #pragma unroll
        for (int t = 0; t < 2; ++t) W[s][t] = cvtpk(p[4 * s + 2 * t], p[4 * s + 2 * t + 1]);
      #pragma unroll
      for (int s = 0; s < 4; ++s)
        #pragma unroll
        for (int t = 0; t < 2; ++t) X[s][t] = __shfl_xor(W[s][t], 32);

      const bool h1 = (hi == 1);
      uint4 pw0, pw1;  // B-frag chunk c: k = 16c + 8*hi + {0..7}
      pw0.x = h1 ? X[1][0] : W[0][0];
      pw0.y = h1 ? X[1][1] : W[0][1];
      pw0.z = h1 ? W[1][0] : X[0][0];
      pw0.w = h1 ? W[1][1] : X[0][1];
      pw1.x = h1 ? X[3][0] : W[2][0];
      pw1.y = h1 ? X[3][1] : W[2][1];
      pw1.z = h1 ? W[3][0] : X[2][0];
      pw1.w = h1 ? W[3][1] : X[2][1];
      bf16x8 pb0 = *(bf16x8*)&pw0, pb1 = *(bf16x8*)&pw1;

      // O^T += V^T @ P^T : 2 k-chunks x 2 d-halves
      {
        bf16x8 v00 = *(const bf16x8*)&Vs[buf][(0 * 2 + 0) * 512 + lane * 8];
        bf16x8 v01 = *(const bf16x8*)&Vs[buf][(0 * 2 + 1) * 512 + lane * 8];
        bf16x8 v10 = *(const bf16x8*)&Vs[buf][(1 * 2 + 0) * 512 + lane * 8];
        bf16x8 v11 = *(const bf16x8*)&Vs[buf][(1 * 2 + 1) * 512 + lane * 8];
        oc0 = __builtin_amdgcn_mfma_f32_32x32x16_bf16(v00, pb0, oc0, 0, 0, 0);
        oc1 = __builtin_amdgcn_mfma_f32_32x32x16_bf16(v01, pb0, oc1, 0, 0, 0);
        oc0 = __builtin_amdgcn_mfma_f32_32x32x16_bf16(v10, pb1, oc0, 0, 0, 0);
        oc1 = __builtin_amdgcn_mfma_f32_32x32x16_bf16(v11, pb1, oc1, 0, 0, 0);
      }
      asm volatile("s_waitcnt lgkmcnt(0)" ::: "memory");
      __builtin_amdgcn_s_barrier();
    }

    // epilogue: lane owns q = qloc; o-reg r -> d = (r&3) + 8*(r>>2) + 4*hi (+32 for oc1)
    float inv = 1.f / lsum;
    #pragma unroll
    for (int dh = 0; dh < 2; ++dh)
      #pragma unroll
      for (int g = 0; g < 4; ++g) {
        ushort4 sv;
        float v0 = (dh ? oc1[4 * g + 0] : oc0[4 * g + 0]) * inv;
        float v1 = (dh ? oc1[4 * g + 1] : oc0[4 * g + 1]) * inv;
        float v2 = (dh ? oc1[4 * g + 2] : oc0[4 * g + 2]) * inv;
        float v3 = (dh ? oc1[4 * g + 3] : oc0[4 * g + 3]) * inv;
        sv.x = f2b(v0); sv.y = f2b(v1); sv.z = f2b(v2); sv.w = f2b(v3);
        *(ushort4*)&Cx[qrow * CD + h * 64 + dh * 32 + 8 * g + 4 * hi] = sv;
      }
  }
}

// ---------------- launch ----------------
extern "C" void kernel_launch(void* const* d_in, const int* in_sizes, int n_in,
                              void* d_out, int out_size, void* d_ws, size_t ws_size,
                              hipStream_t stream) {
  const float* x  = (const float*)d_in[0];
  const float* Wq = (const float*)d_in[1];
  const float* Wk = (const float*)d_in[2];
  const float* Wv = (const float*)d_in[3];
  const float* Wo = (const float*)d_in[4];
  const float* bo = (const float*)d_in[5];
  float* out = (float*)d_out;

  char* W = (char*)d_ws;
  unsigned short* xb  = (unsigned short*)(W);                 // 16 MB
  unsigned short* WqT = (unsigned short*)(W + (16u << 20));   // 2 MB (contig with Wk,Wv)
  unsigned short* WkT = (unsigned short*)(W + (18u << 20));
  unsigned short* WvT = (unsigned short*)(W + (20u << 20));
  unsigned short* WoT = (unsigned short*)(W + (22u << 20));
  unsigned short* Qm  = (unsigned short*)(W + (24u << 20));   // (B,T,C)
  unsigned short* Km  = (unsigned short*)(W + (40u << 20));   // (B,T,C)
  unsigned short* Vt  = (unsigned short*)(W + (56u << 20));   // (B,H,D,T)
  unsigned short* Cx  = (unsigned short*)(W + (72u << 20));   // (B,T,C)

  hipLaunchKernelGGL(cast_x_k, dim3(4096), dim3(256), 0, stream, x, xb);
  hipLaunchKernelGGL(castT_k, dim3(32, 32, 4), dim3(256), 0, stream,
                     Wq, Wk, Wv, Wo, WqT, WkT, WvT, WoT);
  // fused QKV projection: Bt = [WqT;WkT;WvT] rows 0..3071
  hipLaunchKernelGGL((gemm_k<3>), dim3(64, 24), dim3(256), 0, stream,
                     xb, WqT, (void*)Qm, (void*)Km, (void*)Vt, (const float*)nullptr);
  hipLaunchKernelGGL(attn_k, dim3(8, 64), dim3(256), 0, stream, Qm, Km, Vt, Cx);
  hipLaunchKernelGGL((gemm_k<2>), dim3(64, 8), dim3(256), 0, stream,
                     Cx, WoT, (void*)out, nullptr, nullptr, bo);
}